// Round 1
// 266.363 us; speedup vs baseline: 1.0296x; 1.0296x over previous
//
#include <hip/hip_runtime.h>
#include <stdint.h>

#define NPATHS 4096
#define LPATH  8
#define DIM    256
#define HID    256

typedef short  short4v __attribute__((ext_vector_type(4)));
typedef short  short8v __attribute__((ext_vector_type(8)));
typedef float  float4v __attribute__((ext_vector_type(4)));

__device__ __forceinline__ unsigned short f2bf(float f) {
    union { float f; uint32_t u; } v; v.f = f;
    uint32_t u = v.u;
    u += 0x7FFFu + ((u >> 16) & 1u);   // round-to-nearest-even
    return (unsigned short)(u >> 16);
}
__device__ __forceinline__ float bf2f(unsigned short s) {
    return __uint_as_float(((uint32_t)s) << 16);
}
__device__ __forceinline__ float fast_sigmoid(float x) {
    return 1.0f / (1.0f + __expf(-x));
}
__device__ __forceinline__ float fast_tanh(float x) {
    x = fminf(15.0f, fmaxf(-15.0f, x));
    float e = __expf(2.0f * x);
    return (e - 1.0f) / (e + 1.0f);
}
// monotone float<->uint encoding for atomicMax over signed floats
__device__ __forceinline__ unsigned int encf(float f) {
    unsigned int u = __float_as_uint(f);
    return (u & 0x80000000u) ? ~u : (u | 0x80000000u);
}
__device__ __forceinline__ float decf(unsigned int u) {
    return (u & 0x80000000u) ? __uint_as_float(u & 0x7FFFFFFFu) : __uint_as_float(~u);
}

// async global->LDS DMA, 16 B/lane (global_load_lds_dwordx4).
// Global addresses are per-lane; LDS dest is wave-uniform base + lane*16.
__device__ __forceinline__ void dma16(void* lds, const void* g) {
    typedef const unsigned int __attribute__((address_space(1)))* gp_t;
    typedef unsigned int __attribute__((address_space(3)))* lp_t;
    gp_t gp = reinterpret_cast<gp_t>(reinterpret_cast<uintptr_t>(g));
    lp_t lp = reinterpret_cast<lp_t>(static_cast<unsigned int>(reinterpret_cast<uintptr_t>(lds)));
    __builtin_amdgcn_global_load_lds(gp, lp, 16, 0, 0);
}

__device__ __forceinline__ short8v pack8(float4 a, float4 b) {
    short8v r;
    r[0] = (short)f2bf(a.x); r[1] = (short)f2bf(a.y);
    r[2] = (short)f2bf(a.z); r[3] = (short)f2bf(a.w);
    r[4] = (short)f2bf(b.x); r[5] = (short)f2bf(b.y);
    r[6] = (short)f2bf(b.z); r[7] = (short)f2bf(b.w);
    return r;
}

// ---------------------------------------------------------------------------
// K0 (slimmed): blocks 0..511 pack weights into B-fragment order + bias +
// zero logits/path_emb; blocks 512..767 gather+convert slab 0 of Xb only.
// Slabs 1..7 are gathered inside step kernels t=0..6 (overlapped with MFMA,
// and written by the XCD that will read them -> L2-warm A staging).
// WfB (shorts): [(g*16+kc)][unit][quad*8+j] -> step wave load is coalesced.
// ---------------------------------------------------------------------------
__global__ void prep_gather(const float* __restrict__ w_ih, const float* __restrict__ w_hh,
                            const float* __restrict__ b_ih, const float* __restrict__ b_hh,
                            const float* __restrict__ embedding, const int* __restrict__ paths,
                            unsigned short* __restrict__ WfB, float* __restrict__ bias,
                            unsigned int* __restrict__ logits_enc, float* __restrict__ path_emb,
                            unsigned short* __restrict__ Xb) {
    int bid = blockIdx.x;
    if (bid < 512) {
        int gid  = bid * 256 + threadIdx.x;    // 0..131071
        int base = gid * 4;                    // short index, %4==0
        int j0   = base & 31;                  // quad*8+j
        int unit = (base >> 5) & 255;
        int gkc  = base >> 13;                 // g*16+kc, 0..63
        int g    = gkc >> 4, kc = gkc & 15;
        int row  = g * 256 + unit;
        int k    = kc * 32 + j0;
        const float* src = (k < DIM) ? (w_ih + (size_t)row * DIM + k)
                                     : (w_hh + (size_t)row * HID + (k - DIM));
        float4 v = *(const float4*)src;
        short4v pk = {(short)f2bf(v.x), (short)f2bf(v.y), (short)f2bf(v.z), (short)f2bf(v.w)};
        *(short4v*)(WfB + base) = pk;
        if (gid < 1024) bias[gid] = b_ih[gid] + b_hh[gid];
        if (gid < NPATHS) logits_enc[gid] = 0u;
        if (gid < 256) path_emb[gid] = 0.0f;
    } else {
        // slab-0 gather: 256 blocks x 16 rows, XCD-matched to the step
        // kernel's reader blocks (sb%8 == ptile%8).
        int sb   = bid - 512;                        // 0..255
        int row  = (sb & 63) * 64 + (sb >> 6) * 16 + (threadIdx.x >> 4);
        int c0   = (threadIdx.x & 15) * 16;          // 16 floats per thread
        int node = paths[row * LPATH];               // t = 0
        const float* src = embedding + (size_t)node * DIM + c0;
        float4 g0 = *(const float4*)(src + 0);
        float4 g1 = *(const float4*)(src + 4);
        float4 g2 = *(const float4*)(src + 8);
        float4 g3 = *(const float4*)(src + 12);
        unsigned short* xd = Xb + (size_t)row * 256 + c0;
        *(short8v*)(xd)     = pack8(g0, g1);
        *(short8v*)(xd + 8) = pack8(g2, g3);
    }
}

// ---------------------------------------------------------------------------
// K1..K8: one LSTM step. 256 blocks x 256 threads.
// Block = (ptile 0..63, utile 0..3): paths p0..p0+63, units u0..u0+63.
//   blk%8 = ptile%8 (a ptile's 4 blocks share an XCD for h/Xb L2 locality).
// Wave w: 16 units (u0+w*16+l15), all 4 gates, all 64 path rows.
//
// R8 restructure (phase overlap; was: load-everything -> vmcnt(0) -> MFMA):
//   phase 0: x-half DMA (kc 0..7) + B ring kc 0..3 + bias      -> sync1
//   phase 1: issue h-half DMA + gather loads (slab t+1) + c_g prefetch,
//            MFMA kc 0..7 with B ring loads kc 4..11 streamed under them
//            -> sync2 (drains h-DMA under ~2.5k cyc of MFMA)
//   phase 2: MFMA kc 8..15, B ring 12..15 in-loop
//   tail: pointwise (c already in regs), c store, gather convert+store,
//         hT transpose into DEDICATED 9 KB buffer (no pre-write barrier),
//         sync3, coalesced h store, logits (LAST).
// B ring = 4-deep (64 VGPR vs 256): load lead 4 kc ~ 1240 cyc >> L2 latency.
// NOTE (R7 lesson): do NOT fuse steps with in-kernel grid barriers — agent
// fences writeback/invalidate all 8 per-XCD L2s (~40 µs each, 260 MB refetch).
// Kernel-boundary sync keeps L2 warm and costs only the ~2-3 µs launch gap.
// ---------------------------------------------------------------------------
template<bool FIRST, bool LAST>
__global__ __launch_bounds__(256, 1)
void step_kernel(unsigned short* __restrict__ Xb,           // [8][4096][256]
                 const unsigned short* __restrict__ WfB,    // frag-ordered
                 const float* __restrict__ bias,            // [1024]
                 const unsigned short* __restrict__ h_in,   // [4096][256] bf16
                 unsigned short* __restrict__ h_out,        // [4096][256] bf16
                 float* __restrict__ c_g,                   // [4096][256] fp32
                 unsigned int* __restrict__ logits_enc,     // [4096] (LAST)
                 const float* __restrict__ embedding,
                 const int* __restrict__ paths,
                 int t) {
    __shared__ __align__(16) short sA[64 * 512];   // 64 frags x 64 lanes x 8 shorts
    __shared__ __align__(16) short hTb[64 * 72];   // dedicated transpose buffer

    const int tid   = threadIdx.x;
    const int wave  = tid >> 6;
    const int lane  = tid & 63;
    const int l15   = lane & 15;
    const int quad  = lane >> 4;
    const int blk   = blockIdx.x;
    const int ptile = blk & 63;
    const int utile = blk >> 6;
    const int p0    = ptile * 64;
    const int u0    = utile * 64;
    const int unit  = u0 + wave * 16 + l15;

    // ---- phase 0: x-half DMA (frags kc 0..7), B ring 0..3, bias ----
    {
        const char* xl = (const char*)Xb + ((size_t)t * NPATHS + p0) * 512
                       + l15 * 512 + quad * 16;
#pragma unroll
        for (int m = 0; m < 8; ++m) {
            int rf = m >> 1, kq = m & 1;
            int fp = rf * 16 + kq * 4 + wave;              // wave-uniform dest
            dma16(sA + fp * 512, xl + rf * 8192 + (kq * 4 + wave) * 64);
        }
    }

    short8v Bs[4][4];                                      // 4-deep kc ring
    float bb[4];
    auto loadB = [&](int kc) {
#pragma unroll
        for (int g = 0; g < 4; ++g)
            Bs[g][kc & 3] = *(const short8v*)(WfB + (((g * 16 + kc) * 256 + unit) * 32 + quad * 8));
    };
#pragma unroll
    for (int g = 0; g < 4; ++g) bb[g] = bias[g * 256 + unit];
#pragma unroll
    for (int kc = 0; kc < 4; ++kc) loadB(kc);

    __syncthreads();   // sync1: x-half + B0..3 resident

    // ---- phase 1 head: h-half DMA, gather loads, c prefetch (all drained
    //      by sync2, hidden under kc 0..7 MFMA) ----
    if (!FIRST) {
        const char* hl = (const char*)h_in + (size_t)p0 * 512 + l15 * 512 + quad * 16;
#pragma unroll
        for (int m = 0; m < 8; ++m) {
            int rf = m >> 1, kq = m & 1;
            int fp = rf * 16 + 8 + kq * 4 + wave;
            dma16(sA + fp * 512, hl + rf * 8192 + (kq * 4 + wave) * 64);
        }
    }

    float4 gvf[4];
    int grow = 0;
    if (!LAST) {   // gather slab t+1 (16 rows/block, XCD-matched to reader)
        grow = p0 + utile * 16 + (tid >> 4);
        int node = paths[grow * LPATH + (t + 1)];
        const float* src = embedding + (size_t)node * DIM + (tid & 15) * 16;
#pragma unroll
        for (int i = 0; i < 4; ++i) gvf[i] = *(const float4*)(src + i * 4);
    }

    float cpre[16];
    if (!FIRST) {
#pragma unroll
        for (int rf = 0; rf < 4; ++rf)
#pragma unroll
            for (int r = 0; r < 4; ++r)
                cpre[rf * 4 + r] = c_g[(size_t)(p0 + rf * 16 + quad * 4 + r) * HID + unit];
    }

    // ---- MFMA: 64 paths x 256 gate-cols, K=512 (256 at t=0) ----
    float4v acc[4][4];
    const float4v z4 = {0.0f, 0.0f, 0.0f, 0.0f};
#pragma unroll
    for (int rf = 0; rf < 4; ++rf)
#pragma unroll
        for (int g = 0; g < 4; ++g) acc[rf][g] = z4;

    auto kstep = [&](int kc) {
#pragma unroll
        for (int rf = 0; rf < 4; ++rf) {
            short8v a = *(const short8v*)(sA + ((rf * 16 + kc) << 9) + lane * 8);
#pragma unroll
            for (int g = 0; g < 4; ++g)
                acc[rf][g] = __builtin_amdgcn_mfma_f32_16x16x32_bf16(
                    a, Bs[g][kc & 3], acc[rf][g], 0, 0, 0);
        }
    };

#pragma unroll
    for (int kc = 0; kc < 8; ++kc) {       // phase 1: x-half
        kstep(kc);
        int nk = kc + 4;
        if (nk < (FIRST ? 8 : 16)) loadB(nk);
    }

    __syncthreads();   // sync2: h-half resident; half-0 reads done everywhere

    if (!FIRST) {
#pragma unroll
        for (int kc = 8; kc < 16; ++kc) {  // phase 2: h-half
            kstep(kc);
            int nk = kc + 4;
            if (nk < 16) loadB(nk);
        }
    }

    // ---- pointwise LSTM update (i,f,g,o same-lane; c prefetched) ----
    float hv[16];
#pragma unroll
    for (int rf = 0; rf < 4; ++rf) {
#pragma unroll
        for (int r = 0; r < 4; ++r) {
            int row = rf * 16 + quad * 4 + r;       // block-local path row
            int idx = rf * 4 + r;
            float iv = acc[rf][0][r] + bb[0];
            float fv = acc[rf][1][r] + bb[1];
            float gg = acc[rf][2][r] + bb[2];
            float ov = acc[rf][3][r] + bb[3];
            float cp = FIRST ? 0.0f : cpre[idx];
            float cn = fast_sigmoid(fv) * cp + fast_sigmoid(iv) * fast_tanh(gg);
            if (!LAST) c_g[(size_t)(p0 + row) * HID + unit] = cn;
            hv[idx] = fast_sigmoid(ov) * fast_tanh(cn);
        }
    }

    // ---- gather convert+store (slab t+1) ----
    if (!LAST) {
        unsigned short* xd = Xb + ((size_t)(t + 1) * NPATHS + grow) * 256 + (tid & 15) * 16;
        *(short8v*)(xd)     = pack8(gvf[0], gvf[1]);
        *(short8v*)(xd + 8) = pack8(gvf[2], gvf[3]);
    }

    // ---- coalesced h write via dedicated hT buffer (no pre-write barrier) ----
#pragma unroll
    for (int rf = 0; rf < 4; ++rf)
#pragma unroll
        for (int r = 0; r < 4; ++r)
            hTb[(rf * 16 + quad * 4 + r) * 72 + wave * 16 + l15] =
                (short)f2bf(hv[rf * 4 + r]);
    __syncthreads();   // sync3
    {
        unsigned short* hdst = h_out + (size_t)p0 * HID + u0;
#pragma unroll
        for (int i = 0; i < 2; ++i) {
            int cid = i * 256 + tid;              // 0..511
            int row = cid >> 3, seg = cid & 7;
            short8v v = *(const short8v*)(hTb + row * 72 + seg * 8);
            *(short8v*)(hdst + (size_t)row * HID + seg * 8) = v;
        }
    }

    if (LAST) {
        // per-path max over this wave's 16 units -> atomicMax (encoded)
#pragma unroll
        for (int idx = 0; idx < 16; ++idx) {
            float m = hv[idx];
            m = fmaxf(m, __shfl_xor(m, 1, 64));
            m = fmaxf(m, __shfl_xor(m, 2, 64));
            m = fmaxf(m, __shfl_xor(m, 4, 64));
            m = fmaxf(m, __shfl_xor(m, 8, 64));
            if (l15 == 0) {
                int rf = idx >> 2, r = idx & 3;
                atomicMax(&logits_enc[p0 + rf * 16 + quad * 4 + r], encf(m));
            }
        }
    }
}

// ---------------------------------------------------------------------------
// K9: fused softmax + attention partial sums. 256 blocks x 256 threads;
// each block redundantly computes the global softmax scalars from the 16 KB
// logits array (L2-resident), then accumulates its 16 paths into path_emb.
// ---------------------------------------------------------------------------
__global__ void attn_sum_kernel(const unsigned short* __restrict__ h_final,
                                const unsigned int* __restrict__ enc,
                                float* __restrict__ path_emb) {
    __shared__ float red[256];
    __shared__ float wts[16];
    int tid = threadIdx.x;
    int p0  = blockIdx.x * 16;

    float vals[16];
    float m = -1e30f;
#pragma unroll
    for (int i = 0; i < 16; ++i) {
        vals[i] = decf(enc[i * 256 + tid]);
        m = fmaxf(m, vals[i]);
    }
    red[tid] = m; __syncthreads();
    for (int s = 128; s > 0; s >>= 1) {
        if (tid < s) red[tid] = fmaxf(red[tid], red[tid + s]);
        __syncthreads();
    }
    m = red[0]; __syncthreads();
    float sum = 0.0f;
#pragma unroll
    for (int i = 0; i < 16; ++i) sum += __expf(vals[i] - m);
    red[tid] = sum; __syncthreads();
    for (int s = 128; s > 0; s >>= 1) {
        if (tid < s) red[tid] += red[tid + s];
        __syncthreads();
    }
    if (tid == 0) red[0] = 1.0f / red[0];
    __syncthreads();
    float invZ = red[0];
    if (tid < 16) wts[tid] = __expf(decf(enc[p0 + tid]) - m) * invZ;
    __syncthreads();

    float acc = 0.0f;
#pragma unroll
    for (int j = 0; j < 16; ++j)
        acc += wts[j] * bf2f(h_final[(size_t)(p0 + j) * HID + tid]);
    atomicAdd(&path_emb[tid], acc);
}

// ---------------------------------------------------------------------------
// K10: out = sigmoid([user|item|path_emb] . w_lin + b_lin)
// ---------------------------------------------------------------------------
__global__ void final_kernel(const float* __restrict__ embedding,
                             const int* __restrict__ user_id,
                             const int* __restrict__ item_id,
                             const float* __restrict__ w_lin,
                             const float* __restrict__ b_lin,
                             const float* __restrict__ path_emb,
                             float* __restrict__ out) {
    __shared__ float red[256];
    int tid = threadIdx.x;
    int u  = user_id[0];
    int it = item_id[0];
    float s = w_lin[tid]       * embedding[(size_t)u  * DIM + tid]
            + w_lin[256 + tid] * embedding[(size_t)it * DIM + tid]
            + w_lin[512 + tid] * path_emb[tid];
    red[tid] = s; __syncthreads();
    for (int st = 128; st > 0; st >>= 1) {
        if (tid < st) red[tid] += red[tid + st];
        __syncthreads();
    }
    if (tid == 0) out[0] = 1.0f / (1.0f + __expf(-(red[0] + b_lin[0])));
}

// ---------------------------------------------------------------------------
extern "C" void kernel_launch(void* const* d_in, const int* in_sizes, int n_in,
                              void* d_out, int out_size, void* d_ws, size_t ws_size,
                              hipStream_t stream) {
    const float* embedding = (const float*)d_in[0];
    const float* w_ih      = (const float*)d_in[1];
    const float* w_hh      = (const float*)d_in[2];
    const float* b_ih      = (const float*)d_in[3];
    const float* b_hh      = (const float*)d_in[4];
    const float* w_lin     = (const float*)d_in[5];
    const float* b_lin     = (const float*)d_in[6];
    const int*   paths     = (const int*)d_in[7];
    const int*   user_id   = (const int*)d_in[8];
    const int*   item_id   = (const int*)d_in[9];
    float* outp = (float*)d_out;

    // workspace layout (~25.1 MB), 256-B aligned
    char* ws = (char*)d_ws;
    size_t off = 0;
    auto alloc = [&](size_t n) { void* p = ws + off; off = (off + n + 255) & ~(size_t)255; return p; };
    unsigned short* WfB       = (unsigned short*)alloc((size_t)1024 * 512 * 2);           // 1 MB
    float*          bias      = (float*)alloc(1024 * 4);                                  // 4 KB
    unsigned int*   logits_enc= (unsigned int*)alloc(NPATHS * 4);                         // 16 KB
    float*          path_emb  = (float*)alloc(HID * 4);                                   // 1 KB
    unsigned short* Xb        = (unsigned short*)alloc((size_t)LPATH * NPATHS * DIM * 2); // 16 MB
    unsigned short* h_buf     = (unsigned short*)alloc((size_t)2 * NPATHS * HID * 2);     // 4 MB
    float*          c_g       = (float*)alloc((size_t)NPATHS * HID * 4);                  // 4 MB

    // prep: weights (512 blocks) + slab-0 gather (256 blocks)
    prep_gather<<<768, 256, 0, stream>>>(w_ih, w_hh, b_ih, b_hh, embedding, paths,
                                         WfB, bias, logits_enc, path_emb, Xb);

    for (int t = 0; t < LPATH; ++t) {
        const unsigned short* hin = h_buf + (size_t)(t & 1) * NPATHS * HID;
        unsigned short*      hout = h_buf + (size_t)((t + 1) & 1) * NPATHS * HID;
        if (t == 0)
            step_kernel<true, false><<<256, 256, 0, stream>>>(Xb, WfB, bias, hin, hout,
                                                              c_g, logits_enc,
                                                              embedding, paths, t);
        else if (t == LPATH - 1)
            step_kernel<false, true><<<256, 256, 0, stream>>>(Xb, WfB, bias, hin, hout,
                                                              c_g, logits_enc,
                                                              embedding, paths, t);
        else
            step_kernel<false, false><<<256, 256, 0, stream>>>(Xb, WfB, bias, hin, hout,
                                                               c_g, logits_enc,
                                                               embedding, paths, t);
    }

    // final h is in h_buf plane 0 (8 steps of ping-pong)
    attn_sum_kernel<<<NPATHS / 16, 256, 0, stream>>>(h_buf, logits_enc, path_emb);
    final_kernel<<<1, 256, 0, stream>>>(embedding, user_id, item_id, w_lin, b_lin,
                                        path_emb, outp);
}